// Round 3
// baseline (393.309 us; speedup 1.0000x reference)
//
#include <hip/hip_runtime.h>

#define HBITS 19u
#define HSIZE (1u << HBITS)
#define HMASK (HSIZE - 1u)
#define ECAP  (1 << 20)           // extras capacity (pairs)
#define EMPTY64 0xFFFFFFFFFFFFFFFFull

constexpr int CD = 41, CH = 1024, CW = 1024;

// ---------------- setup: clear hash table, flags, counters ----------------

__global__ __launch_bounds__(256) void setup(unsigned long long* __restrict__ tab,
                                             int* __restrict__ flags, int n,
                                             int* __restrict__ cnt, int* __restrict__ scnt) {
    unsigned i = blockIdx.x * blockDim.x + threadIdx.x;
    if (i < HSIZE) tab[i] = EMPTY64;
    if (i < (unsigned)n) flags[i] = 0;
    if (i == 0) { *cnt = 0; *scnt = 0; }
}

// ---------------- hash: 64-bit records (idx<<32 | lin), linear probe ----------------

__global__ __launch_bounds__(256) void hash_insert(const int* __restrict__ coors, int n,
                                                   unsigned long long* __restrict__ tab) {
    int i = blockIdx.x * blockDim.x + threadIdx.x;
    if (i >= n) return;
    int b = coors[4 * i], z = coors[4 * i + 1], y = coors[4 * i + 2], x = coors[4 * i + 3];
    unsigned lin = (((unsigned)b * CD + (unsigned)z) * CH + (unsigned)y) * CW + (unsigned)x;
    unsigned h = (lin * 2654435761u) >> (32u - HBITS);
    unsigned long long rec = ((unsigned long long)(unsigned)i << 32) | (unsigned long long)lin;
    while (true) {
        unsigned long long prev = atomicCAS(&tab[h], EMPTY64, rec);
        if (prev == EMPTY64) break;
        h = (h + 1u) & HMASK;
    }
}

__device__ __forceinline__ int hash_lookup(unsigned lin, const unsigned long long* __restrict__ tab) {
    unsigned h = (lin * 2654435761u) >> (32u - HBITS);
    while (true) {
        unsigned long long v = tab[h];
        if ((unsigned)v == lin) return (int)(v >> 32);
        if (v == EMPTY64) return -1;
        h = (h + 1u) & HMASK;
    }
}

// ---------------- extras + S membership (mirror symmetry, scan k<13) ----------------

__global__ __launch_bounds__(256) void build_extras(const int* __restrict__ coors, int n,
                                                    const unsigned long long* __restrict__ tab,
                                                    int2* __restrict__ extras,
                                                    int* __restrict__ cnt,
                                                    int* __restrict__ flags) {
    int i = blockIdx.x * blockDim.x + threadIdx.x;
    if (i >= n) return;
    int b = coors[4 * i], z = coors[4 * i + 1], y = coors[4 * i + 2], x = coors[4 * i + 3];
    for (int k = 0; k < 13; ++k) {
        int dz = k / 9 - 1, dy = (k / 3) % 3 - 1, dx = k % 3 - 1;
        int nz = z + dz, ny = y + dy, nx = x + dx;
        if (nz < 0 || nz >= CD || ny < 0 || ny >= CH || nx < 0 || nx >= CW) continue;
        unsigned lin = (((unsigned)b * CD + (unsigned)nz) * CH + (unsigned)ny) * CW + (unsigned)nx;
        int j = hash_lookup(lin, tab);
        if (j >= 0) {
            int pos = atomicAdd(cnt, 2);
            if (pos + 1 < ECAP) {
                extras[pos]     = make_int2((i << 5) | k,        j);
                extras[pos + 1] = make_int2((j << 5) | (26 - k), i);
                flags[i] = 1;
                flags[j] = 1;
            }
        }
    }
}

__global__ __launch_bounds__(256) void compact_S(const int* __restrict__ flags, int n,
                                                 int* __restrict__ Slist, int* __restrict__ scnt) {
    int i = blockIdx.x * blockDim.x + threadIdx.x;
    if (i < n && flags[i]) { int s = atomicAdd(scnt, 1); Slist[s] = i; }
}

// ---------------- mm64: C = A @ B, 64x64 row-major, 16 blocks x 256 ----------------

__global__ __launch_bounds__(256) void mm64(const float* __restrict__ A,
                                            const float* __restrict__ B,
                                            float* __restrict__ C) {
    int e = blockIdx.x * 256 + threadIdx.x;
    int r = e >> 6, c = e & 63;
    float s0 = 0.f, s1 = 0.f;
#pragma unroll
    for (int k = 0; k < 64; k += 2) {
        s0 = fmaf(A[r * 64 + k],     B[k * 64 + c],       s0);
        s1 = fmaf(A[r * 64 + k + 1], B[(k + 1) * 64 + c], s1);
    }
    C[e] = s0 + s1;
}

// ---------------- tiled row-GEMM: out[p] = x[p] @ Wm  (Wm row-major [cin][cout]) ----
// 128 points/block. LDS-staged X with float4 rotate-swizzle; lane=point;
// channel-half wave-uniform -> Wm rows via s_load; 32 independent accumulators.

__device__ __forceinline__ int xidx4(int row, int c4) {   // float index of logical c4 block
    return (row << 6) + (((c4 + row) & 15) << 2);
}

__global__ __launch_bounds__(256) void gemm_tile(const float* __restrict__ xin,
                                                 float* __restrict__ xout,
                                                 const float* __restrict__ Wm,
                                                 const int* __restrict__ list,     // null -> identity
                                                 const int* __restrict__ listCnt,  // null -> n
                                                 int n) {
    __shared__ float Xs[128 * 64];
    int t = threadIdx.x;
    int cnt = listCnt ? *listCnt : n;
    if (cnt <= 0) return;
    int ntiles = (cnt + 127) >> 7;

    int lane = t & 63;
    int w = t >> 6;
    int g = __builtin_amdgcn_readfirstlane(w >> 1);        // point-group (0/1)
    int h = __builtin_amdgcn_readfirstlane(w & 1) << 5;    // channel half (0/32)
    int crow = (g << 6) + lane;                            // local row this lane computes

    int addrA[16];                                         // per-lane swizzled addrs by logical c4
#pragma unroll
    for (int a = 0; a < 16; ++a) addrA[a] = xidx4(crow, a);

    for (int tile = blockIdx.x; tile < ntiles; tile += gridDim.x) {
        int base = tile << 7;
        __syncthreads();                                   // tile-reuse guard
#pragma unroll
        for (int it = 0; it < 8; ++it) {                   // global -> LDS, coalesced
            int f = it * 1024 + t * 4;
            int row = f >> 6, c = f & 63;
            int gr = base + row;
            int src = list ? list[min(gr, cnt - 1)] : min(gr, cnt - 1);
            float4 v = *(const float4*)(xin + (size_t)src * 64 + c);
            *(float4*)&Xs[xidx4(row, c >> 2)] = v;
        }
        __syncthreads();

        float acc[32];
#pragma unroll
        for (int o = 0; o < 32; ++o) acc[o] = 0.f;
#pragma unroll
        for (int c4 = 0; c4 < 16; ++c4) {
            float4 xv = *(const float4*)&Xs[addrA[c4]];    // logical channels 4*c4..+3
#pragma unroll
            for (int b = 0; b < 4; ++b) {
                int c = c4 * 4 + b;
                float xc = b == 0 ? xv.x : b == 1 ? xv.y : b == 2 ? xv.z : xv.w;
                const float* wr = Wm + (c << 6) + h;       // wave-uniform -> s_load
#pragma unroll
                for (int o = 0; o < 32; ++o) acc[o] = fmaf(xc, wr[o], acc[o]);
            }
        }
        __syncthreads();
#pragma unroll
        for (int a = 0; a < 8; ++a) {                      // acc -> LDS (same swizzle)
            float4 v = make_float4(acc[a * 4], acc[a * 4 + 1], acc[a * 4 + 2], acc[a * 4 + 3]);
            *(float4*)&Xs[addrA[(h >> 2) + a]] = v;
        }
        __syncthreads();
#pragma unroll
        for (int it = 0; it < 8; ++it) {                   // LDS -> global, coalesced
            int f = it * 1024 + t * 4;
            int row = f >> 6, c = f & 63;
            int gr = base + row;
            if (gr < cnt) {
                int dst = list ? list[gr] : gr;
                float4 v = *(const float4*)&Xs[xidx4(row, c >> 2)];
                *(float4*)(xout + (size_t)dst * 64 + c) = v;
            }
        }
    }
}

// ---------------- sparse residual: out[i] += x[j] @ W[k] per extra pair ----------------

__global__ __launch_bounds__(256) void residual(const float* __restrict__ xin,
                                                float* __restrict__ xout,
                                                const float* __restrict__ Wl,   // [27][64][64]
                                                const int2* __restrict__ extras,
                                                const int* __restrict__ cnt) {
    int m = *cnt; if (m > ECAP) m = ECAP;
    int nw = (int)((gridDim.x * blockDim.x) >> 6);
    int gw = (int)((blockIdx.x * blockDim.x + threadIdx.x) >> 6);
    int lane = threadIdx.x & 63;
    for (int e = gw; e < m; e += nw) {
        int2 pr = extras[e];
        int i = pr.x >> 5, k = pr.x & 31, j = pr.y;
        float xj = xin[(size_t)j * 64 + lane];
        const float* Wk = Wl + k * 4096;
        float a0 = 0.f, a1 = 0.f;
#pragma unroll
        for (int c = 0; c < 64; c += 2) {
            a0 = fmaf(__shfl(xj, c),     Wk[c * 64 + lane],       a0);
            a1 = fmaf(__shfl(xj, c + 1), Wk[(c + 1) * 64 + lane], a1);
        }
        atomicAdd(&xout[(size_t)i * 64 + lane], a0 + a1);
    }
}

// ---------------- launch ----------------

extern "C" void kernel_launch(void* const* d_in, const int* in_sizes, int n_in,
                              void* d_out, int out_size, void* d_ws, size_t ws_size,
                              hipStream_t stream) {
    const float* features = (const float*)d_in[0];
    const float* Ws       = (const float*)d_in[1];   // [3][27][64][64]
    const int*   coors    = (const int*)d_in[2];
    int n = in_sizes[0] / 64;

    char* p = (char*)d_ws;
    unsigned long long* tab = (unsigned long long*)p; p += (size_t)HSIZE * 8;
    int* cnt  = (int*)p;
    int* scnt = cnt + 1;                              p += 256;
    int2* extras = (int2*)p;                          p += (size_t)ECAP * 8;
    int* flags = (int*)p;                             p += (((size_t)n * 4 + 255) & ~255ull);
    int* Slist = (int*)p;                             p += (((size_t)n * 4 + 255) & ~255ull);
    float* bufA = (float*)p;                          p += (((size_t)n * 256 + 255) & ~255ull);
    float* bufB = (float*)p;                          p += (((size_t)n * 256 + 255) & ~255ull);
    float* T  = (float*)p;                            p += 16384;
    float* P  = (float*)p;                            p += 16384;
    float* out = (float*)d_out;

    const float* W0  = Ws + 0 * 27 * 4096;
    const float* W1  = Ws + 1 * 27 * 4096;
    const float* W2  = Ws + 2 * 27 * 4096;
    const float* W0c = W0 + 13 * 4096;
    const float* W1c = W1 + 13 * 4096;
    const float* W2c = W2 + 13 * 4096;

    setup<<<(HSIZE + 255) / 256, 256, 0, stream>>>(tab, flags, n, cnt, scnt);
    hash_insert<<<(n + 255) / 256, 256, 0, stream>>>(coors, n, tab);
    mm64<<<16, 256, 0, stream>>>(W0c, W1c, T);       // T = W0c @ W1c
    mm64<<<16, 256, 0, stream>>>(T, W2c, P);         // P = T @ W2c
    build_extras<<<(n + 255) / 256, 256, 0, stream>>>(coors, n, tab, extras, cnt, flags);
    compact_S<<<(n + 255) / 256, 256, 0, stream>>>(flags, n, Slist, scnt);

    // dense collapsed 3-layer pass: out = features @ P
    int dtiles = (n + 127) / 128;
    gemm_tile<<<dtiles, 256, 0, stream>>>(features, out, P, nullptr, nullptr, n);

    // S-pass (closed set): true per-layer propagation, then overwrite out rows
    gemm_tile<<<64, 256, 0, stream>>>(features, bufA, W0c, Slist, scnt, n);
    residual<<<128, 256, 0, stream>>>(features, bufA, W0, extras, cnt);
    gemm_tile<<<64, 256, 0, stream>>>(bufA, bufB, W1c, Slist, scnt, n);
    residual<<<128, 256, 0, stream>>>(bufA, bufB, W1, extras, cnt);
    gemm_tile<<<64, 256, 0, stream>>>(bufB, out, W2c, Slist, scnt, n);
    residual<<<128, 256, 0, stream>>>(bufB, out, W2, extras, cnt);
}

// Round 4
// 225.847 us; speedup vs baseline: 1.7415x; 1.7415x over previous
//
#include <hip/hip_runtime.h>

#define HBITS 19u
#define HSIZE (1u << HBITS)
#define HMASK (HSIZE - 1u)
#define ECAP  (1 << 20)           // extras capacity (entries)
#define EMPTY64 0xFFFFFFFFFFFFFFFFull

constexpr int CD = 41, CH = 1024, CW = 1024;

// ---------------- setup: clear hash table, flags, counters ----------------

__global__ __launch_bounds__(256) void setup(unsigned long long* __restrict__ tab,
                                             int* __restrict__ flags, int n,
                                             int* __restrict__ cnt, int* __restrict__ scnt) {
    unsigned i = blockIdx.x * blockDim.x + threadIdx.x;
    if (i < HSIZE) tab[i] = EMPTY64;
    if (i < (unsigned)n) flags[i] = 0;
    if (i == 0) { *cnt = 0; *scnt = 0; }
}

// ---------------- hash: 64-bit records (idx<<32 | lin), linear probe ----------------

__global__ __launch_bounds__(256) void hash_insert(const int* __restrict__ coors, int n,
                                                   unsigned long long* __restrict__ tab) {
    int i = blockIdx.x * blockDim.x + threadIdx.x;
    if (i >= n) return;
    int b = coors[4 * i], z = coors[4 * i + 1], y = coors[4 * i + 2], x = coors[4 * i + 3];
    unsigned lin = (((unsigned)b * CD + (unsigned)z) * CH + (unsigned)y) * CW + (unsigned)x;
    unsigned h = (lin * 2654435761u) >> (32u - HBITS);
    unsigned long long rec = ((unsigned long long)(unsigned)i << 32) | (unsigned long long)lin;
    while (true) {
        unsigned long long prev = atomicCAS(&tab[h], EMPTY64, rec);
        if (prev == EMPTY64) break;
        h = (h + 1u) & HMASK;
    }
}

__device__ __forceinline__ int hash_lookup(unsigned lin, const unsigned long long* __restrict__ tab) {
    unsigned h = (lin * 2654435761u) >> (32u - HBITS);
    while (true) {
        unsigned long long v = tab[h];
        if ((unsigned)v == lin) return (int)(v >> 32);
        if (v == EMPTY64) return -1;
        h = (h + 1u) & HMASK;
    }
}

// ---------------- extras + S membership (mirror symmetry, scan k<13) ----------------

__global__ __launch_bounds__(256) void build_extras(const int* __restrict__ coors, int n,
                                                    const unsigned long long* __restrict__ tab,
                                                    int2* __restrict__ extras,
                                                    int* __restrict__ cnt,
                                                    int* __restrict__ flags) {
    int i = blockIdx.x * blockDim.x + threadIdx.x;
    if (i >= n) return;
    int b = coors[4 * i], z = coors[4 * i + 1], y = coors[4 * i + 2], x = coors[4 * i + 3];
    for (int k = 0; k < 13; ++k) {
        int dz = k / 9 - 1, dy = (k / 3) % 3 - 1, dx = k % 3 - 1;
        int nz = z + dz, ny = y + dy, nx = x + dx;
        if (nz < 0 || nz >= CD || ny < 0 || ny >= CH || nx < 0 || nx >= CW) continue;
        unsigned lin = (((unsigned)b * CD + (unsigned)nz) * CH + (unsigned)ny) * CW + (unsigned)nx;
        int j = hash_lookup(lin, tab);
        if (j >= 0) {
            int pos = atomicAdd(cnt, 2);
            if (pos + 1 < ECAP) {
                extras[pos]     = make_int2((i << 5) | k,        j);
                extras[pos + 1] = make_int2((j << 5) | (26 - k), i);
                flags[i] = 1;
                flags[j] = 1;
            }
        }
    }
}

__global__ __launch_bounds__(256) void compact_S(const int* __restrict__ flags, int n,
                                                 int* __restrict__ Slist, int* __restrict__ scnt) {
    int i = blockIdx.x * blockDim.x + threadIdx.x;
    if (i < n && flags[i]) { int s = atomicAdd(scnt, 1); Slist[s] = i; }
}

// ---------------- mm64: C = A @ B, 64x64 row-major ----------------

__global__ __launch_bounds__(256) void mm64(const float* __restrict__ A,
                                            const float* __restrict__ B,
                                            float* __restrict__ C) {
    int e = blockIdx.x * 256 + threadIdx.x;
    int r = e >> 6, c = e & 63;
    float s0 = 0.f, s1 = 0.f;
#pragma unroll
    for (int k = 0; k < 64; k += 2) {
        s0 = fmaf(A[r * 64 + k],     B[k * 64 + c],       s0);
        s1 = fmaf(A[r * 64 + k + 1], B[(k + 1) * 64 + c], s1);
    }
    C[e] = s0 + s1;
}

// ---------------- row GEMM: out[p] = x[p] @ Wm (row-major [cin][cout]) ----------------
// lane = out channel. W column in 16 NAMED float4s (registers, no arrays/casts).
// Point id wave-uniform (readfirstlane) -> x row reads are scalar loads (SMEM pipe).
// 4 points/iter, 2 accumulators each -> 8 independent FMA chains. Coalesced stores.

#define WL(q) make_float4(Wc[(4*(q)+0)*64], Wc[(4*(q)+1)*64], Wc[(4*(q)+2)*64], Wc[(4*(q)+3)*64])

#define FMAQ(q, acc, xr) do { \
    acc = fmaf((xr)[4*(q)+0], w##q.x, acc); \
    acc = fmaf((xr)[4*(q)+1], w##q.y, acc); \
    acc = fmaf((xr)[4*(q)+2], w##q.z, acc); \
    acc = fmaf((xr)[4*(q)+3], w##q.w, acc); } while (0)

#define FMA_LO(acc, xr) do { FMAQ(0,acc,xr); FMAQ(1,acc,xr); FMAQ(2,acc,xr); FMAQ(3,acc,xr); \
                             FMAQ(4,acc,xr); FMAQ(5,acc,xr); FMAQ(6,acc,xr); FMAQ(7,acc,xr); } while (0)
#define FMA_HI(acc, xr) do { FMAQ(8,acc,xr); FMAQ(9,acc,xr); FMAQ(10,acc,xr); FMAQ(11,acc,xr); \
                             FMAQ(12,acc,xr); FMAQ(13,acc,xr); FMAQ(14,acc,xr); FMAQ(15,acc,xr); } while (0)

#define POINT(u) do { \
    int iu = base + (u); \
    int qu = iu < cnt ? iu : cnt - 1; \
    int pu = list ? list[qu] : qu; \
    pu = __builtin_amdgcn_readfirstlane(pu); \
    const float* xr = xin + (size_t)pu * 64; \
    float aL = 0.f, aH = 0.f; \
    FMA_LO(aL, xr); \
    FMA_HI(aH, xr); \
    if (iu < cnt) xout[(size_t)pu * 64 + lane] = aL + aH; \
} while (0)

__global__ __launch_bounds__(256) void gemm_rows(const float* __restrict__ xin,
                                                 float* __restrict__ xout,
                                                 const float* __restrict__ Wm,
                                                 const int* __restrict__ list,     // null -> identity
                                                 const int* __restrict__ listCnt,  // null -> n
                                                 int n) {
    int lane = threadIdx.x & 63;
    int wv  = (int)((blockIdx.x * blockDim.x + threadIdx.x) >> 6);
    int nwv = (int)((gridDim.x * blockDim.x) >> 6);
    int cnt = listCnt ? *listCnt : n;
    if (cnt <= 0) return;

    const float* Wc = Wm + lane;
    float4 w0  = WL(0),  w1  = WL(1),  w2  = WL(2),  w3  = WL(3);
    float4 w4  = WL(4),  w5  = WL(5),  w6  = WL(6),  w7  = WL(7);
    float4 w8  = WL(8),  w9  = WL(9),  w10 = WL(10), w11 = WL(11);
    float4 w12 = WL(12), w13 = WL(13), w14 = WL(14), w15 = WL(15);

    int ngrp = (cnt + 3) >> 2;
    for (int grp = wv; grp < ngrp; grp += nwv) {
        int base = __builtin_amdgcn_readfirstlane(grp) << 2;
        POINT(0);
        POINT(1);
        POINT(2);
        POINT(3);
    }
}

// ---------------- sparse residual: out[i] += x[j] @ W[k] per extra entry ----------------
// x row via uniform scalar loads; W row read coalesced (lane = out channel).

__global__ __launch_bounds__(256) void residual(const float* __restrict__ xin,
                                                float* __restrict__ xout,
                                                const float* __restrict__ Wl,   // [27][64][64]
                                                const int2* __restrict__ extras,
                                                const int* __restrict__ cnt) {
    int m = *cnt; if (m > ECAP) m = ECAP;
    int nw = (int)((gridDim.x * blockDim.x) >> 6);
    int gw = (int)((blockIdx.x * blockDim.x + threadIdx.x) >> 6);
    int lane = threadIdx.x & 63;
    for (int e = gw; e < m; e += nw) {
        int eu = __builtin_amdgcn_readfirstlane(e);
        int2 pr = extras[eu];
        int i = __builtin_amdgcn_readfirstlane(pr.x >> 5);
        int k = __builtin_amdgcn_readfirstlane(pr.x & 31);
        int j = __builtin_amdgcn_readfirstlane(pr.y);
        const float* xj = xin + (size_t)j * 64;
        const float* Wk = Wl + k * 4096 + lane;
        float a0 = 0.f, a1 = 0.f;
#pragma unroll
        for (int c = 0; c < 64; c += 2) {
            a0 = fmaf(xj[c],     Wk[c * 64],       a0);
            a1 = fmaf(xj[c + 1], Wk[(c + 1) * 64], a1);
        }
        atomicAdd(&xout[(size_t)i * 64 + lane], a0 + a1);
    }
}

// ---------------- launch ----------------

extern "C" void kernel_launch(void* const* d_in, const int* in_sizes, int n_in,
                              void* d_out, int out_size, void* d_ws, size_t ws_size,
                              hipStream_t stream) {
    const float* features = (const float*)d_in[0];
    const float* Ws       = (const float*)d_in[1];   // [3][27][64][64]
    const int*   coors    = (const int*)d_in[2];
    int n = in_sizes[0] / 64;

    char* p = (char*)d_ws;
    unsigned long long* tab = (unsigned long long*)p; p += (size_t)HSIZE * 8;
    int* cnt  = (int*)p;
    int* scnt = cnt + 1;                              p += 256;
    int2* extras = (int2*)p;                          p += (size_t)ECAP * 8;
    int* flags = (int*)p;                             p += (((size_t)n * 4 + 255) & ~255ull);
    int* Slist = (int*)p;                             p += (((size_t)n * 4 + 255) & ~255ull);
    float* bufA = (float*)p;                          p += (((size_t)n * 256 + 255) & ~255ull);
    float* bufB = (float*)p;                          p += (((size_t)n * 256 + 255) & ~255ull);
    float* T  = (float*)p;                            p += 16384;
    float* P  = (float*)p;                            p += 16384;
    float* out = (float*)d_out;

    const float* W0  = Ws + 0 * 27 * 4096;
    const float* W1  = Ws + 1 * 27 * 4096;
    const float* W2  = Ws + 2 * 27 * 4096;
    const float* W0c = W0 + 13 * 4096;
    const float* W1c = W1 + 13 * 4096;
    const float* W2c = W2 + 13 * 4096;

    setup<<<(HSIZE + 255) / 256, 256, 0, stream>>>(tab, flags, n, cnt, scnt);
    hash_insert<<<(n + 255) / 256, 256, 0, stream>>>(coors, n, tab);
    mm64<<<16, 256, 0, stream>>>(W0c, W1c, T);       // T = W0c @ W1c
    mm64<<<16, 256, 0, stream>>>(T, W2c, P);         // P = T @ W2c
    build_extras<<<(n + 255) / 256, 256, 0, stream>>>(coors, n, tab, extras, cnt, flags);
    compact_S<<<(n + 255) / 256, 256, 0, stream>>>(flags, n, Slist, scnt);

    // dense collapsed 3-layer pass: out = features @ P
    gemm_rows<<<768, 256, 0, stream>>>(features, out, P, nullptr, nullptr, n);

    // S-pass (closed set): per-layer propagation on S rows, then overwrite out rows
    gemm_rows<<<64, 256, 0, stream>>>(features, bufA, W0c, Slist, scnt, n);
    residual<<<64, 256, 0, stream>>>(features, bufA, W0, extras, cnt);
    gemm_rows<<<64, 256, 0, stream>>>(bufA, bufB, W1c, Slist, scnt, n);
    residual<<<64, 256, 0, stream>>>(bufA, bufB, W1, extras, cnt);
    gemm_rows<<<64, 256, 0, stream>>>(bufB, out, W2c, Slist, scnt, n);
    residual<<<64, 256, 0, stream>>>(bufB, out, W2, extras, cnt);
}